// Round 9
// baseline (1898.700 us; speedup 1.0000x reference)
//
#include <hip/hip_runtime.h>
#include <hip/hip_bf16.h>
#include <stdint.h>

typedef __attribute__((ext_vector_type(8))) short short8;
typedef __attribute__((ext_vector_type(4))) float f32x4;

#define AS1 __attribute__((address_space(1)))
#define AS3 __attribute__((address_space(3)))

__device__ __forceinline__ short f2bf(float x) {
    __hip_bfloat16 h = __float2bfloat16(x);
    union { __hip_bfloat16 h; short s; } u; u.h = h; return u.s;
}

__device__ __forceinline__ void gload_lds16(const short* g, short* l) {
    __builtin_amdgcn_global_load_lds((const AS1 void*)g, (AS3 void*)l, 16, 0, 0);
}

#define VMCNT0_BAR() asm volatile("s_waitcnt vmcnt(0)\n\ts_barrier" ::: "memory")

// ---------------------------------------------------------------------------
// 256x256 tile, BK=64 K-tiles, 512 threads = 8 waves (2M x 4N).
// LDS [2buf][2kh][256][32] x {A,B} = 128 KiB; T2 chunk-XOR swizzle (0
// conflicts measured). r9: ONE sync per K-tile (vmcnt(0)+barrier; the stage
// was issued a full tile ~3000 cy earlier so the drain is free), then
// stage(t+1) + 24 ds_read_b128 + 64 MFMA in a single unfenced region.
// Rationale: r5/r6/r8 all measured ~45% MfmaUtil = zero read/MFMA overlap --
// per-tile 5018 cy ~= MFMA 2484 + LDS-port 2313 + sync, i.e. phase barriers
// lockstep all 8 waves into {all-read}/{all-MFMA} regions. With no intra-tile
// fences the compiler software-pipelines (hoists next chunk's reads above
// this chunk's MFMAs with fine-grained lgkmcnt -- m97 asm-verified) and waves
// skew so LDS port time hides under the MFMA pipe.
// Hazard audit: reads(t-1, buf nb) complete before their consuming MFMAs
// (lgkm), which precede barrier(t); stage(t+1 -> nb) is issued after
// barrier(t), writes land later. Single barrier/tile is sufficient.
// QKV: block-diagonal merged q/k/v projection -- A col base = n0 & ~1023.
// TAPS==3: conv path; A rows remap through padded [2][8194][4096].
// ---------------------------------------------------------------------------
template<int TAPS, bool QKV, bool F32OUT>
__global__ __launch_bounds__(512, 2) void gemm256(
    const short* __restrict__ A, int lda,
    const short* __restrict__ BT, int ldb, long long tapB,
    void* __restrict__ Cout, int ldc,
    const float* __restrict__ bias, int KT)
{
    __shared__ __align__(16) short As[2 * 2 * 256 * 32];
    __shared__ __align__(16) short Bs[2 * 2 * 256 * 32];
    const int tid = threadIdx.x, lane = tid & 63, wid = tid >> 6;
    const int wm = wid >> 2, wn = wid & 3;
    const int m0 = blockIdx.y * 256, n0 = blockIdx.x * 256;
    const size_t arow0 = (TAPS == 3) ? ((size_t)(m0 >> 13) * 8194 + (size_t)(m0 & 8191))
                                     : (size_t)m0;
    const size_t ldaS = (size_t)lda, ldbS = (size_t)ldb, tapBS = (size_t)tapB;
    const short* Abase0 = A + arow0 * ldaS + (QKV ? (n0 & ~1023) : 0);
    const short* Bbase0 = BT + (size_t)n0 * ldbS;
    const int c15 = lane & 15, g4 = (lane >> 4) * 4;
    const int swz = ((lane >> 4) ^ ((c15 >> 1) & 3)) * 8;
    const int srow = tid >> 2;
    const int schunk = (((tid & 3) ^ ((tid >> 3) & 3)) * 8);

#define STG_A(u, kh, buf) do { \
    const int tp_ = (TAPS == 3) ? ((u) >> 6) : 0; \
    const int kc_ = (TAPS == 3) ? (((u) & 63) << 6) : ((u) << 6); \
    const short* g_ = Abase0 + (size_t)tp_ * ldaS + kc_ + (kh) * 32 \
                      + (size_t)srow * ldaS + schunk; \
    short* l_ = As + (buf) * 16384 + (kh) * 8192 + wid * 512; \
    gload_lds16(g_, l_); \
    gload_lds16(g_ + 128 * ldaS, l_ + 4096); \
} while (0)

#define STG_B(u, kh, buf) do { \
    const int tp_ = (TAPS == 3) ? ((u) >> 6) : 0; \
    const int kc_ = (TAPS == 3) ? (((u) & 63) << 6) : ((u) << 6); \
    const short* g_ = Bbase0 + (size_t)tp_ * tapBS + kc_ + (kh) * 32 \
                      + (size_t)srow * ldbS + schunk; \
    short* l_ = Bs + (buf) * 16384 + (kh) * 8192 + wid * 512; \
    gload_lds16(g_, l_); \
    gload_lds16(g_ + 128 * ldbS, l_ + 4096); \
} while (0)

#define LDA_(buf, kk, mi) (*(const short8*)(As + (buf) * 16384 + (kk) * 8192 \
                           + (wm * 128 + (mi) * 16 + c15) * 32 + swz))
#define LDB_(buf, kk, nj) (*(const short8*)(Bs + (buf) * 16384 + (kk) * 8192 \
                           + (wn * 64 + (nj) * 16 + c15) * 32 + swz))

#define MM(mi, nj, Av, Bv) acc[mi][nj] = \
    __builtin_amdgcn_mfma_f32_16x16x32_bf16(Av, Bv, acc[mi][nj], 0, 0, 0)

#define MFMA16(MB) do { \
    MM((MB)+0, 0, a0, b0); MM((MB)+0, 1, a0, b1); MM((MB)+0, 2, a0, b2); MM((MB)+0, 3, a0, b3); \
    MM((MB)+1, 0, a1, b0); MM((MB)+1, 1, a1, b1); MM((MB)+1, 2, a1, b2); MM((MB)+1, 3, a1, b3); \
    MM((MB)+2, 0, a2, b0); MM((MB)+2, 1, a2, b1); MM((MB)+2, 2, a2, b2); MM((MB)+2, 3, a2, b3); \
    MM((MB)+3, 0, a3, b0); MM((MB)+3, 1, a3, b1); MM((MB)+3, 2, a3, b2); MM((MB)+3, 3, a3, b3); \
} while (0)

    f32x4 acc[8][4];
    #pragma unroll
    for (int i = 0; i < 8; ++i)
        #pragma unroll
        for (int j = 0; j < 4; ++j)
            acc[i][j] = (f32x4){0.f, 0.f, 0.f, 0.f};

    // prologue: stage tile 0 into buf 0 (8 loads/wave)
    STG_A(0, 0, 0); STG_B(0, 0, 0); STG_A(0, 1, 0); STG_B(0, 1, 0);

    for (int t = 0; t < KT; ++t) {
        const int c = t & 1, nb = c ^ 1;
        VMCNT0_BAR();   // tile t resident (staged a full tile earlier)
        if (t + 1 < KT) {
            STG_A(t + 1, 0, nb); STG_B(t + 1, 0, nb);
            STG_A(t + 1, 1, nb); STG_B(t + 1, 1, nb);
        }
        short8 a0, a1, a2, a3, b0, b1, b2, b3;
        // kk0, mi0-3
        a0 = LDA_(c, 0, 0); a1 = LDA_(c, 0, 1); a2 = LDA_(c, 0, 2); a3 = LDA_(c, 0, 3);
        b0 = LDB_(c, 0, 0); b1 = LDB_(c, 0, 1); b2 = LDB_(c, 0, 2); b3 = LDB_(c, 0, 3);
        MFMA16(0);
        // kk0, mi4-7 (b reused)
        a0 = LDA_(c, 0, 4); a1 = LDA_(c, 0, 5); a2 = LDA_(c, 0, 6); a3 = LDA_(c, 0, 7);
        MFMA16(4);
        // kk1, mi0-3
        a0 = LDA_(c, 1, 0); a1 = LDA_(c, 1, 1); a2 = LDA_(c, 1, 2); a3 = LDA_(c, 1, 3);
        b0 = LDB_(c, 1, 0); b1 = LDB_(c, 1, 1); b2 = LDB_(c, 1, 2); b3 = LDB_(c, 1, 3);
        MFMA16(0);
        // kk1, mi4-7
        a0 = LDA_(c, 1, 4); a1 = LDA_(c, 1, 5); a2 = LDA_(c, 1, 6); a3 = LDA_(c, 1, 7);
        MFMA16(4);
    }

    float bv[4];
    #pragma unroll
    for (int nj = 0; nj < 4; ++nj)
        bv[nj] = bias ? bias[n0 + wn * 64 + nj * 16 + c15] : 0.f;
    #pragma unroll
    for (int mi = 0; mi < 8; ++mi) {
        #pragma unroll
        for (int r = 0; r < 4; ++r) {
            const size_t row = (size_t)m0 + wm * 128 + mi * 16 + g4 + r;
            #pragma unroll
            for (int nj = 0; nj < 4; ++nj) {
                const int col = n0 + wn * 64 + nj * 16 + c15;
                const float v = acc[mi][nj][r] + bv[nj];
                if (F32OUT) ((float*)Cout)[row * (size_t)ldc + col] = v;
                else        ((short*)Cout)[row * (size_t)ldc + col] = f2bf(v);
            }
        }
    }
#undef STG_A
#undef STG_B
#undef LDA_
#undef LDB_
#undef MM
#undef MFMA16
}

// ---------------------------------------------------------------------------
// Per (head, block) causal attention. qkvh: [16384][3072] bf16, q at cols
// 0-1023, k at +1024, v at +2048 (col within each = h*64+e). obuf [16384][1024].
// ---------------------------------------------------------------------------
__global__ __launch_bounds__(256) void attn_kernel(
    const short* __restrict__ qkvh, short* __restrict__ obuf)
{
    __shared__ __align__(16) char smem[54272];
    short* qs = (short*)smem;                 // [128][72]
    short* ks = (short*)smem + 9216;          // [128][72]
    short* vt = (short*)(smem + 36864);       // [64][136]  (v transposed)
    short* ps = (short*)smem;                 // [128][136] (reuses qs+ks region)
    short* os = (short*)smem;                 // [128][72]  (reused post-PV)

    const int tid = threadIdx.x, lane = tid & 63, wid = tid >> 6;
    const int h = blockIdx.x, b = blockIdx.y;
    const size_t base = (size_t)b * 128 * 3072 + (size_t)h * 64;

    for (int i = tid; i < 1024; i += 256) {
        const int row = i >> 3, c8 = i & 7;
        const size_t g = base + (size_t)row * 3072 + c8 * 8;
        *(short8*)(qs + row * 72 + c8 * 8) = *(const short8*)(qkvh + g);
        *(short8*)(ks + row * 72 + c8 * 8) = *(const short8*)(qkvh + g + 1024);
        short8 vv = *(const short8*)(qkvh + g + 2048);
        #pragma unroll
        for (int j = 0; j < 8; ++j) vt[(c8 * 8 + j) * 136 + row] = vv[j];
    }
    __syncthreads();

    const int c15 = lane & 15, g8 = (lane >> 4) * 8, g4 = (lane >> 4) * 4;
    const int r0 = wid * 32;

    f32x4 sacc[2][8];
    #pragma unroll
    for (int mi = 0; mi < 2; ++mi)
        #pragma unroll
        for (int nj = 0; nj < 8; ++nj)
            sacc[mi][nj] = (f32x4){0.f, 0.f, 0.f, 0.f};
    #pragma unroll
    for (int kk = 0; kk < 2; ++kk) {
        short8 aq[2];
        #pragma unroll
        for (int mi = 0; mi < 2; ++mi)
            aq[mi] = *(const short8*)(qs + (r0 + mi * 16 + c15) * 72 + kk * 32 + g8);
        #pragma unroll
        for (int nj = 0; nj < 8; ++nj) {
            short8 bk8 = *(const short8*)(ks + (nj * 16 + c15) * 72 + kk * 32 + g8);
            #pragma unroll
            for (int mi = 0; mi < 2; ++mi)
                sacc[mi][nj] = __builtin_amdgcn_mfma_f32_16x16x32_bf16(
                    aq[mi], bk8, sacc[mi][nj], 0, 0, 0);
        }
    }
    __syncthreads();

    #pragma unroll
    for (int mi = 0; mi < 2; ++mi) {
        #pragma unroll
        for (int r = 0; r < 4; ++r) {
            const int qrow = r0 + mi * 16 + g4 + r;
            float m = -3.0e38f, pv[8];
            #pragma unroll
            for (int nj = 0; nj < 8; ++nj) {
                float s = sacc[mi][nj][r] * 0.125f;
                if (nj * 16 + c15 > qrow) s = -1.0e9f;
                pv[nj] = s; m = fmaxf(m, s);
            }
            #pragma unroll
            for (int off = 8; off >= 1; off >>= 1) m = fmaxf(m, __shfl_xor(m, off));
            float sum = 0.f;
            #pragma unroll
            for (int nj = 0; nj < 8; ++nj) { float p = __expf(pv[nj] - m); pv[nj] = p; sum += p; }
            #pragma unroll
            for (int off = 8; off >= 1; off >>= 1) sum += __shfl_xor(sum, off);
            const float inv = 1.0f / sum;
            #pragma unroll
            for (int nj = 0; nj < 8; ++nj)
                ps[qrow * 136 + nj * 16 + c15] = f2bf(pv[nj] * inv);
        }
    }
    __syncthreads();

    f32x4 oacc[2][4];
    #pragma unroll
    for (int mi = 0; mi < 2; ++mi)
        #pragma unroll
        for (int nj = 0; nj < 4; ++nj)
            oacc[mi][nj] = (f32x4){0.f, 0.f, 0.f, 0.f};
    #pragma unroll
    for (int kt = 0; kt < 4; ++kt) {
        short8 ap[2];
        #pragma unroll
        for (int mi = 0; mi < 2; ++mi)
            ap[mi] = *(const short8*)(ps + (r0 + mi * 16 + c15) * 136 + kt * 32 + g8);
        #pragma unroll
        for (int nj = 0; nj < 4; ++nj) {
            short8 bv8 = *(const short8*)(vt + (nj * 16 + c15) * 136 + kt * 32 + g8);
            #pragma unroll
            for (int mi = 0; mi < 2; ++mi)
                oacc[mi][nj] = __builtin_amdgcn_mfma_f32_16x16x32_bf16(
                    ap[mi], bv8, oacc[mi][nj], 0, 0, 0);
        }
    }
    __syncthreads();

    #pragma unroll
    for (int mi = 0; mi < 2; ++mi)
        #pragma unroll
        for (int r = 0; r < 4; ++r)
            #pragma unroll
            for (int nj = 0; nj < 4; ++nj)
                os[(r0 + mi * 16 + g4 + r) * 72 + nj * 16 + c15] = f2bf(oacc[mi][nj][r]);
    __syncthreads();

    for (int i = tid; i < 1024; i += 256) {
        const int row = i >> 3, c8 = i & 7;
        *(short8*)(obuf + (size_t)b * 128 * 1024 + (size_t)h * 64
                   + (size_t)row * 1024 + c8 * 8) =
            *(const short8*)(os + row * 72 + c8 * 8);
    }
}

// ---------------------------------------------------------------------------
__global__ void pad_convert_inputs(const float* __restrict__ in, short* __restrict__ out)
{
    const int row = blockIdx.x;                 // [0, 16388)
    const int n = row / 8194, l = row % 8194;
    short* orow = out + (size_t)row * 4096;
    if (l == 0 || l == 8193) {
        for (int i = threadIdx.x; i < 512; i += 256) {
            uint4 z; z.x = z.y = z.z = z.w = 0u;
            *(uint4*)(orow + i * 8) = z;
        }
    } else {
        const float* irow = in + ((size_t)n * 8192 + (l - 1)) * 4096;
        for (int i = threadIdx.x; i < 512; i += 256) {
            float4 a = *(const float4*)(irow + i * 8);
            float4 b = *(const float4*)(irow + i * 8 + 4);
            short8 v;
            v[0] = f2bf(a.x); v[1] = f2bf(a.y); v[2] = f2bf(a.z); v[3] = f2bf(a.w);
            v[4] = f2bf(b.x); v[5] = f2bf(b.y); v[6] = f2bf(b.z); v[7] = f2bf(b.w);
            *(short8*)(orow + i * 8) = v;
        }
    }
}

__global__ void transpose_convert(const float* __restrict__ in, short* __restrict__ out,
                                  int R, int C)
{
    __shared__ float tile[32][33];
    const int tx = threadIdx.x & 31, ty = threadIdx.x >> 5;   // 32 x 8
    const int bx = blockIdx.x * 32, by = blockIdx.y * 32;
    #pragma unroll
    for (int i = 0; i < 32; i += 8)
        tile[ty + i][tx] = in[(size_t)(by + ty + i) * C + bx + tx];
    __syncthreads();
    #pragma unroll
    for (int i = 0; i < 32; i += 8)
        out[(size_t)(bx + ty + i) * R + by + tx] = f2bf(tile[tx][ty + i]);
}

__global__ void convert_bf16(const float* __restrict__ in, short* __restrict__ out, int n8)
{
    const int idx = blockIdx.x * 256 + threadIdx.x;
    if (idx < n8) {
        float4 a = *(const float4*)(in + (size_t)idx * 8);
        float4 b = *(const float4*)(in + (size_t)idx * 8 + 4);
        short8 v;
        v[0] = f2bf(a.x); v[1] = f2bf(a.y); v[2] = f2bf(a.z); v[3] = f2bf(a.w);
        v[4] = f2bf(b.x); v[5] = f2bf(b.y); v[6] = f2bf(b.z); v[7] = f2bf(b.w);
        *(short8*)(out + (size_t)idx * 8) = v;
    }
}

__global__ void fuse_bias(const float* __restrict__ bo, const float* __restrict__ projw,
                          const float* __restrict__ projb, float* __restrict__ outb)
{
    const int j = blockIdx.x * 256 + threadIdx.x;   // 4096
    float s = projb[j];
    for (int w = 0; w < 1024; ++w) s = fmaf(bo[w], projw[(size_t)w * 4096 + j], s);
    outb[j] = s;
}

__global__ void concat_bias(const float* __restrict__ bq, const float* __restrict__ bk,
                            const float* __restrict__ bv, float* __restrict__ outb)
{
    const int j = blockIdx.x * 256 + threadIdx.x;   // 3072
    outb[j] = (j < 1024) ? bq[j] : (j < 2048) ? bk[j - 1024] : bv[j - 2048];
}

// ---------------------------------------------------------------------------
extern "C" void kernel_launch(void* const* d_in, const int* in_sizes, int n_in,
                              void* d_out, int out_size, void* d_ws, size_t ws_size,
                              hipStream_t stream)
{
    const float* inputs = (const float*)d_in[0];
    const float* conv_w = (const float*)d_in[1];
    const float* conv_b = (const float*)d_in[2];
    const float* wq     = (const float*)d_in[3];
    const float* bq     = (const float*)d_in[4];
    const float* wk     = (const float*)d_in[5];
    const float* bk     = (const float*)d_in[6];
    const float* wv     = (const float*)d_in[7];
    const float* bv     = (const float*)d_in[8];
    const float* wo     = (const float*)d_in[9];
    const float* bo     = (const float*)d_in[10];
    const float* proj_w = (const float*)d_in[11];
    const float* proj_b = (const float*)d_in[12];

    char* ws = (char*)d_ws;
    short* in_pad = (short*)(ws + 0);             // [2][8194][4096]
    short* w_bf   = (short*)(ws + 134283264);     // [3][3072][4096] BT
    short* qkv    = (short*)(ws + 209780736);     // [16384][3072] conv out
    short* wq_t   = (short*)(ws + 310444032);     // [3][1024][1024] BT contiguous
    short* wo_bf  = (short*)(ws + 316735488);     // [1024][1024]
    short* proj_t = (short*)(ws + 318832640);     // [4096][1024]
    short* WfT    = (short*)(ws + 327221248);     // [4096][1024]
    float* bfused = (float*)(ws + 335609856);     // [4096]
    float* bqkv   = (float*)(ws + 335626240);     // [3072]
    short* qkvh   = (short*)(ws + 0);             // [16384][3072] over in_pad
    short* o_buf  = (short*)(ws + 134283264);     // [16384][1024] over w_bf

    dim3 blk(256), blk5(512);

    pad_convert_inputs<<<16388, blk, 0, stream>>>(inputs, in_pad);
    for (int t = 0; t < 3; ++t)
        transpose_convert<<<dim3(96, 128), blk, 0, stream>>>(
            conv_w + (size_t)t * 4096 * 3072, w_bf + (size_t)t * 3072 * 4096, 4096, 3072);
    transpose_convert<<<dim3(32, 32), blk, 0, stream>>>(wq, wq_t, 1024, 1024);
    transpose_convert<<<dim3(32, 32), blk, 0, stream>>>(wk, wq_t + 1048576, 1024, 1024);
    transpose_convert<<<dim3(32, 32), blk, 0, stream>>>(wv, wq_t + 2097152, 1024, 1024);
    transpose_convert<<<dim3(128, 32), blk, 0, stream>>>(proj_w, proj_t, 1024, 4096);
    convert_bf16<<<512, blk, 0, stream>>>(wo, wo_bf, 131072);
    fuse_bias<<<16, blk, 0, stream>>>(bo, proj_w, proj_b, bfused);
    concat_bias<<<12, blk, 0, stream>>>(bq, bk, bv, bqkv);

    // WfT[dm][he] = sum_w proj_t[dm][w] * wo_flat[he][w]
    gemm256<1, false, false><<<dim3(4, 16), blk5, 0, stream>>>(
        proj_t, 1024, wo_bf, 1024, 0, WfT, 1024, nullptr, 16);
    // conv as 3-tap GEMM -> qkv [16384][3072]
    gemm256<3, false, false><<<dim3(12, 64), blk5, 0, stream>>>(
        in_pad, 4096, w_bf, 4096, (long long)3072 * 4096, qkv, 3072, conv_b, 192);
    // merged block-diagonal q/k/v head projections -> qkvh [16384][3072]
    gemm256<1, true, false><<<dim3(12, 64), blk5, 0, stream>>>(
        qkv, 3072, wq_t, 1024, 0, qkvh, 3072, bqkv, 16);

    attn_kernel<<<dim3(16, 128), blk, 0, stream>>>(qkvh, o_buf);

    // out = o @ Wf + bfused   (f32 out)
    gemm256<1, false, true><<<dim3(16, 64), blk5, 0, stream>>>(
        o_buf, 1024, WfT, 1024, 0, d_out, 4096, bfused, 16);
}

// Round 10
// 1672.578 us; speedup vs baseline: 1.1352x; 1.1352x over previous
//
#include <hip/hip_runtime.h>
#include <hip/hip_bf16.h>
#include <stdint.h>

typedef __attribute__((ext_vector_type(8))) short short8;
typedef __attribute__((ext_vector_type(4))) float f32x4;

#define AS1 __attribute__((address_space(1)))
#define AS3 __attribute__((address_space(3)))

__device__ __forceinline__ short f2bf(float x) {
    __hip_bfloat16 h = __float2bfloat16(x);
    union { __hip_bfloat16 h; short s; } u; u.h = h; return u.s;
}

__device__ __forceinline__ void gload_lds16(const short* g, short* l) {
    __builtin_amdgcn_global_load_lds((const AS1 void*)g, (AS3 void*)l, 16, 0, 0);
}

#define BAR()        asm volatile("s_barrier" ::: "memory")
#define VMCNT_BAR(N) asm volatile("s_waitcnt vmcnt(" #N ")\n\ts_barrier" ::: "memory")

// ---------------------------------------------------------------------------
// r5 schedule (best measured: 46.8% MfmaUtil, 0 bank conflicts) -- 256x256
// tile, BK=64, 8 waves (2M x 4N), 4 phases split on mi, reads-after-sync,
// counted vmcnt(4), T2 chunk-XOR swizzle, setprio around MFMA clusters.
// r6(reg-pipeline) 41%, r8(m201-order) 44.5%, r9(unfenced) 39% all regressed
// or neutral -- schedule family exhausted, r5 retained verbatim.
// MODE: 0 = plain; 1 = QKVB (weight-prep: B col base += m0 & ~1023, i.e.
// BT[n][k] = conv_w[t][n][(m0>>10)*1024 + k] -- folds wq/wk/wv into conv_w).
// TAPS==3: conv path; A rows remap through padded [2][8194][4096].
// ---------------------------------------------------------------------------
template<int TAPS, int MODE, bool F32OUT>
__global__ __launch_bounds__(512, 2) void gemm256(
    const short* __restrict__ A, int lda,
    const short* __restrict__ BT, int ldb, long long tapB,
    void* __restrict__ Cout, int ldc,
    const float* __restrict__ bias, int Ktiles)
{
    __shared__ __align__(16) short As[2 * 2 * 256 * 32];
    __shared__ __align__(16) short Bs[2 * 2 * 256 * 32];
    const int tid = threadIdx.x, lane = tid & 63, wid = tid >> 6;
    const int wm = wid >> 2, wn = wid & 3;
    const int m0 = blockIdx.y * 256, n0 = blockIdx.x * 256;
    const size_t arow0 = (TAPS == 3) ? ((size_t)(m0 >> 13) * 8194 + (size_t)(m0 & 8191))
                                     : (size_t)m0;
    const size_t ldaS = (size_t)lda, ldbS = (size_t)ldb, tapBS = (size_t)tapB;
    const short* Abase0 = A + arow0 * ldaS;
    const short* Bbase0 = BT + (size_t)n0 * ldbS + ((MODE == 1) ? (m0 & ~1023) : 0);
    const int c15 = lane & 15, g4 = (lane >> 4) * 4;
    const int swz = ((lane >> 4) ^ ((c15 >> 1) & 3)) * 8;
    const int srow = tid >> 2;
    const int schunk = (((tid & 3) ^ ((tid >> 3) & 3)) * 8);

#define STG_A(u, kh, buf) do { \
    const int tp_ = (TAPS == 3) ? ((u) >> 6) : 0; \
    const int kc_ = (TAPS == 3) ? (((u) & 63) << 6) : ((u) << 6); \
    const short* g_ = Abase0 + (size_t)tp_ * ldaS + kc_ + (kh) * 32 \
                      + (size_t)srow * ldaS + schunk; \
    short* l_ = As + (buf) * 16384 + (kh) * 8192 + wid * 512; \
    gload_lds16(g_, l_); \
    gload_lds16(g_ + 128 * ldaS, l_ + 4096); \
} while (0)

#define STG_B(u, kh, buf) do { \
    const int tp_ = (TAPS == 3) ? ((u) >> 6) : 0; \
    const int kc_ = (TAPS == 3) ? (((u) & 63) << 6) : ((u) << 6); \
    const short* g_ = Bbase0 + (size_t)tp_ * tapBS + kc_ + (kh) * 32 \
                      + (size_t)srow * ldbS + schunk; \
    short* l_ = Bs + (buf) * 16384 + (kh) * 8192 + wid * 512; \
    gload_lds16(g_, l_); \
    gload_lds16(g_ + 128 * ldbS, l_ + 4096); \
} while (0)

#define LDA_(buf, kk, mi) (*(const short8*)(As + (buf) * 16384 + (kk) * 8192 \
                           + (wm * 128 + (mi) * 16 + c15) * 32 + swz))
#define LDB_(buf, kk, nj) (*(const short8*)(Bs + (buf) * 16384 + (kk) * 8192 \
                           + (wn * 64 + (nj) * 16 + c15) * 32 + swz))

// 16 MFMA: af[0..3] x bf4[0..3] -> acc[MB..MB+3][0..3]
#define MFMA4x4(MB) do { \
    __builtin_amdgcn_s_setprio(1); \
    _Pragma("unroll") \
    for (int mi_ = 0; mi_ < 4; ++mi_) \
        _Pragma("unroll") \
        for (int nj_ = 0; nj_ < 4; ++nj_) \
            acc[(MB) + mi_][nj_] = __builtin_amdgcn_mfma_f32_16x16x32_bf16( \
                af[mi_], bf4[nj_], acc[(MB) + mi_][nj_], 0, 0, 0); \
    __builtin_amdgcn_s_setprio(0); \
} while (0)

    f32x4 acc[8][4];
    #pragma unroll
    for (int i = 0; i < 8; ++i)
        #pragma unroll
        for (int j = 0; j < 4; ++j)
            acc[i][j] = (f32x4){0.f, 0.f, 0.f, 0.f};

    // prologue: tile 0, issue order = Akh0, Bkh0, Akh1, Bkh1 (8 loads)
    STG_A(0, 0, 0); STG_B(0, 0, 0); STG_A(0, 1, 0); STG_B(0, 1, 0);
    VMCNT_BAR(4);   // kh0 of tile 0 resident; kh1 (4 loads) still in flight

    for (int t = 0; t < Ktiles; ++t) {
        const int c = t & 1, nb = c ^ 1;
        const bool st = (t + 1 < Ktiles);
        const int u = t + 1;
        short8 af[4], bf4[4];

        // ---- ph0: kk=0, mi 0-3 (+ all 4 b) ----
        #pragma unroll
        for (int mi = 0; mi < 4; ++mi) af[mi] = LDA_(c, 0, mi);
        #pragma unroll
        for (int nj = 0; nj < 4; ++nj) bf4[nj] = LDB_(c, 0, nj);
        if (st) STG_A(u, 0, nb);
        BAR();
        MFMA4x4(0);
        BAR();

        // ---- ph1: kk=0, mi 4-7 (reuse bf4) ----
        #pragma unroll
        for (int mi = 0; mi < 4; ++mi) af[mi] = LDA_(c, 0, 4 + mi);
        if (st) STG_B(u, 0, nb);
        if (st) { VMCNT_BAR(4); } else { VMCNT_BAR(0); }   // kh1(t) resident
        MFMA4x4(4);
        BAR();

        // ---- ph2: kk=1, mi 0-3 (+ all 4 b) ----
        #pragma unroll
        for (int mi = 0; mi < 4; ++mi) af[mi] = LDA_(c, 1, mi);
        #pragma unroll
        for (int nj = 0; nj < 4; ++nj) bf4[nj] = LDB_(c, 1, nj);
        if (st) STG_A(u, 1, nb);
        BAR();
        MFMA4x4(0);
        BAR();

        // ---- ph3: kk=1, mi 4-7 (reuse bf4) ----
        #pragma unroll
        for (int mi = 0; mi < 4; ++mi) af[mi] = LDA_(c, 1, 4 + mi);
        if (st) STG_B(u, 1, nb);
        if (st) { VMCNT_BAR(4); } else { VMCNT_BAR(0); }   // kh0(t+1) resident
        MFMA4x4(4);
        BAR();
    }

    float bv[4];
    #pragma unroll
    for (int nj = 0; nj < 4; ++nj)
        bv[nj] = bias ? bias[n0 + wn * 64 + nj * 16 + c15] : 0.f;
    #pragma unroll
    for (int mi = 0; mi < 8; ++mi) {
        #pragma unroll
        for (int r = 0; r < 4; ++r) {
            const size_t row = (size_t)m0 + wm * 128 + mi * 16 + g4 + r;
            #pragma unroll
            for (int nj = 0; nj < 4; ++nj) {
                const int col = n0 + wn * 64 + nj * 16 + c15;
                const float v = acc[mi][nj][r] + bv[nj];
                if (F32OUT) ((float*)Cout)[row * (size_t)ldc + col] = v;
                else        ((short*)Cout)[row * (size_t)ldc + col] = f2bf(v);
            }
        }
    }
#undef STG_A
#undef STG_B
#undef LDA_
#undef LDB_
#undef MFMA4x4
}

// ---------------------------------------------------------------------------
// Per (head, block) causal attention. qkvh: [16384][3072] bf16, q at cols
// 0-1023, k at +1024, v at +2048 (col within each = h*64+e). obuf [16384][1024].
// ---------------------------------------------------------------------------
__global__ __launch_bounds__(256) void attn_kernel(
    const short* __restrict__ qkvh, short* __restrict__ obuf)
{
    __shared__ __align__(16) char smem[54272];
    short* qs = (short*)smem;                 // [128][72]
    short* ks = (short*)smem + 9216;          // [128][72]
    short* vt = (short*)(smem + 36864);       // [64][136]  (v transposed)
    short* ps = (short*)smem;                 // [128][136] (reuses qs+ks region)
    short* os = (short*)smem;                 // [128][72]  (reused post-PV)

    const int tid = threadIdx.x, lane = tid & 63, wid = tid >> 6;
    const int h = blockIdx.x, b = blockIdx.y;
    const size_t base = (size_t)b * 128 * 3072 + (size_t)h * 64;

    for (int i = tid; i < 1024; i += 256) {
        const int row = i >> 3, c8 = i & 7;
        const size_t g = base + (size_t)row * 3072 + c8 * 8;
        *(short8*)(qs + row * 72 + c8 * 8) = *(const short8*)(qkvh + g);
        *(short8*)(ks + row * 72 + c8 * 8) = *(const short8*)(qkvh + g + 1024);
        short8 vv = *(const short8*)(qkvh + g + 2048);
        #pragma unroll
        for (int j = 0; j < 8; ++j) vt[(c8 * 8 + j) * 136 + row] = vv[j];
    }
    __syncthreads();

    const int c15 = lane & 15, g8 = (lane >> 4) * 8, g4 = (lane >> 4) * 4;
    const int r0 = wid * 32;

    f32x4 sacc[2][8];
    #pragma unroll
    for (int mi = 0; mi < 2; ++mi)
        #pragma unroll
        for (int nj = 0; nj < 8; ++nj)
            sacc[mi][nj] = (f32x4){0.f, 0.f, 0.f, 0.f};
    #pragma unroll
    for (int kk = 0; kk < 2; ++kk) {
        short8 aq[2];
        #pragma unroll
        for (int mi = 0; mi < 2; ++mi)
            aq[mi] = *(const short8*)(qs + (r0 + mi * 16 + c15) * 72 + kk * 32 + g8);
        #pragma unroll
        for (int nj = 0; nj < 8; ++nj) {
            short8 bk8 = *(const short8*)(ks + (nj * 16 + c15) * 72 + kk * 32 + g8);
            #pragma unroll
            for (int mi = 0; mi < 2; ++mi)
                sacc[mi][nj] = __builtin_amdgcn_mfma_f32_16x16x32_bf16(
                    aq[mi], bk8, sacc[mi][nj], 0, 0, 0);
        }
    }
    __syncthreads();

    #pragma unroll
    for (int mi = 0; mi < 2; ++mi) {
        #pragma unroll
        for (int r = 0; r < 4; ++r) {
            const int qrow = r0 + mi * 16 + g4 + r;
            float m = -3.0e38f, pv[8];
            #pragma unroll
            for (int nj = 0; nj < 8; ++nj) {
                float s = sacc[mi][nj][r] * 0.125f;
                if (nj * 16 + c15 > qrow) s = -1.0e9f;
                pv[nj] = s; m = fmaxf(m, s);
            }
            #pragma unroll
            for (int off = 8; off >= 1; off >>= 1) m = fmaxf(m, __shfl_xor(m, off));
            float sum = 0.f;
            #pragma unroll
            for (int nj = 0; nj < 8; ++nj) { float p = __expf(pv[nj] - m); pv[nj] = p; sum += p; }
            #pragma unroll
            for (int off = 8; off >= 1; off >>= 1) sum += __shfl_xor(sum, off);
            const float inv = 1.0f / sum;
            #pragma unroll
            for (int nj = 0; nj < 8; ++nj)
                ps[qrow * 136 + nj * 16 + c15] = f2bf(pv[nj] * inv);
        }
    }
    __syncthreads();

    f32x4 oacc[2][4];
    #pragma unroll
    for (int mi = 0; mi < 2; ++mi)
        #pragma unroll
        for (int nj = 0; nj < 4; ++nj)
            oacc[mi][nj] = (f32x4){0.f, 0.f, 0.f, 0.f};
    #pragma unroll
    for (int kt = 0; kt < 4; ++kt) {
        short8 ap[2];
        #pragma unroll
        for (int mi = 0; mi < 2; ++mi)
            ap[mi] = *(const short8*)(ps + (r0 + mi * 16 + c15) * 136 + kt * 32 + g8);
        #pragma unroll
        for (int nj = 0; nj < 4; ++nj) {
            short8 bv8 = *(const short8*)(vt + (nj * 16 + c15) * 136 + kt * 32 + g8);
            #pragma unroll
            for (int mi = 0; mi < 2; ++mi)
                oacc[mi][nj] = __builtin_amdgcn_mfma_f32_16x16x32_bf16(
                    ap[mi], bv8, oacc[mi][nj], 0, 0, 0);
        }
    }
    __syncthreads();

    #pragma unroll
    for (int mi = 0; mi < 2; ++mi)
        #pragma unroll
        for (int r = 0; r < 4; ++r)
            #pragma unroll
            for (int nj = 0; nj < 4; ++nj)
                os[(r0 + mi * 16 + g4 + r) * 72 + nj * 16 + c15] = f2bf(oacc[mi][nj][r]);
    __syncthreads();

    for (int i = tid; i < 1024; i += 256) {
        const int row = i >> 3, c8 = i & 7;
        *(short8*)(obuf + (size_t)b * 128 * 1024 + (size_t)h * 64
                   + (size_t)row * 1024 + c8 * 8) =
            *(const short8*)(os + row * 72 + c8 * 8);
    }
}

// ---------------------------------------------------------------------------
__global__ void pad_convert_inputs(const float* __restrict__ in, short* __restrict__ out)
{
    const int row = blockIdx.x;                 // [0, 16388)
    const int n = row / 8194, l = row % 8194;
    short* orow = out + (size_t)row * 4096;
    if (l == 0 || l == 8193) {
        for (int i = threadIdx.x; i < 512; i += 256) {
            uint4 z; z.x = z.y = z.z = z.w = 0u;
            *(uint4*)(orow + i * 8) = z;
        }
    } else {
        const float* irow = in + ((size_t)n * 8192 + (l - 1)) * 4096;
        for (int i = threadIdx.x; i < 512; i += 256) {
            float4 a = *(const float4*)(irow + i * 8);
            float4 b = *(const float4*)(irow + i * 8 + 4);
            short8 v;
            v[0] = f2bf(a.x); v[1] = f2bf(a.y); v[2] = f2bf(a.z); v[3] = f2bf(a.w);
            v[4] = f2bf(b.x); v[5] = f2bf(b.y); v[6] = f2bf(b.z); v[7] = f2bf(b.w);
            *(short8*)(orow + i * 8) = v;
        }
    }
}

__global__ void transpose_convert(const float* __restrict__ in, short* __restrict__ out,
                                  int R, int C)
{
    __shared__ float tile[32][33];
    const int tx = threadIdx.x & 31, ty = threadIdx.x >> 5;   // 32 x 8
    const int bx = blockIdx.x * 32, by = blockIdx.y * 32;
    #pragma unroll
    for (int i = 0; i < 32; i += 8)
        tile[ty + i][tx] = in[(size_t)(by + ty + i) * C + bx + tx];
    __syncthreads();
    #pragma unroll
    for (int i = 0; i < 32; i += 8)
        out[(size_t)(bx + ty + i) * R + by + tx] = f2bf(tile[tx][ty + i]);
}

__global__ void convert_bf16(const float* __restrict__ in, short* __restrict__ out, int n8)
{
    const int idx = blockIdx.x * 256 + threadIdx.x;
    if (idx < n8) {
        float4 a = *(const float4*)(in + (size_t)idx * 8);
        float4 b = *(const float4*)(in + (size_t)idx * 8 + 4);
        short8 v;
        v[0] = f2bf(a.x); v[1] = f2bf(a.y); v[2] = f2bf(a.z); v[3] = f2bf(a.w);
        v[4] = f2bf(b.x); v[5] = f2bf(b.y); v[6] = f2bf(b.z); v[7] = f2bf(b.w);
        *(short8*)(out + (size_t)idx * 8) = v;
    }
}

__global__ void fuse_bias(const float* __restrict__ bo, const float* __restrict__ projw,
                          const float* __restrict__ projb, float* __restrict__ outb)
{
    const int j = blockIdx.x * 256 + threadIdx.x;   // 4096
    float s = projb[j];
    for (int w = 0; w < 1024; ++w) s = fmaf(bo[w], projw[(size_t)w * 4096 + j], s);
    outb[j] = s;
}

// b2[o] = b_part[o&1023] + sum_d conv_b[(o>>10)*1024+d] * wpart[d][o&1023]
__global__ void fuse_bias_qkv(const float* __restrict__ conv_b,
                              const float* __restrict__ wq, const float* __restrict__ bq,
                              const float* __restrict__ wk, const float* __restrict__ bk,
                              const float* __restrict__ wv, const float* __restrict__ bv,
                              float* __restrict__ outb)
{
    const int o = blockIdx.x * 256 + threadIdx.x;   // 3072
    const int p = o >> 10, e = o & 1023;
    const float* w = (p == 0) ? wq : (p == 1) ? wk : wv;
    const float* bb = (p == 0) ? bq : (p == 1) ? bk : bv;
    const float* cb = conv_b + p * 1024;
    float s = bb[e];
    for (int d = 0; d < 1024; ++d) s = fmaf(cb[d], w[(size_t)d * 1024 + e], s);
    outb[o] = s;
}

// ---------------------------------------------------------------------------
extern "C" void kernel_launch(void* const* d_in, const int* in_sizes, int n_in,
                              void* d_out, int out_size, void* d_ws, size_t ws_size,
                              hipStream_t stream)
{
    const float* inputs = (const float*)d_in[0];
    const float* conv_w = (const float*)d_in[1];
    const float* conv_b = (const float*)d_in[2];
    const float* wq     = (const float*)d_in[3];
    const float* bq     = (const float*)d_in[4];
    const float* wk     = (const float*)d_in[5];
    const float* bk     = (const float*)d_in[6];
    const float* wv     = (const float*)d_in[7];
    const float* bv     = (const float*)d_in[8];
    const float* wo     = (const float*)d_in[9];
    const float* bo     = (const float*)d_in[10];
    const float* proj_w = (const float*)d_in[11];
    const float* proj_b = (const float*)d_in[12];

    char* ws = (char*)d_ws;
    short* in_pad = (short*)(ws + 0);             // [2][8194][4096]      134,283,264 B
    short* cw_bf  = (short*)(ws + 134283264);     // [3][4096][3072] bf16  75,497,472 B (dead after prep)
    short* qkvh   = (short*)(ws + 134283264);     // [16384][3072] over cw_bf (+ slack to 235,0)
    short* W2T    = (short*)(ws + 234946560);     // [3][3072][4096] bf16  75,497,472 B
    short* wq_t   = (short*)(ws + 310444032);     // [3][1024][1024] BT contiguous
    short* wo_bf  = (short*)(ws + 316735488);     // [1024][1024]
    short* proj_t = (short*)(ws + 318832640);     // [4096][1024]
    short* WfT    = (short*)(ws + 327221248);     // [4096][1024]
    float* bfused = (float*)(ws + 335609856);     // [4096]
    float* b2     = (float*)(ws + 335626240);     // [3072]
    short* o_buf  = (short*)(ws + 0);             // [16384][1024] over in_pad (dead after conv)

    dim3 blk(256), blk5(512);

    pad_convert_inputs<<<16388, blk, 0, stream>>>(inputs, in_pad);
    convert_bf16<<<18432, blk, 0, stream>>>(conv_w, cw_bf, 4718592);   // straight convert
    transpose_convert<<<dim3(32, 32), blk, 0, stream>>>(wq, wq_t, 1024, 1024);
    transpose_convert<<<dim3(32, 32), blk, 0, stream>>>(wk, wq_t + 1048576, 1024, 1024);
    transpose_convert<<<dim3(32, 32), blk, 0, stream>>>(wv, wq_t + 2097152, 1024, 1024);
    transpose_convert<<<dim3(128, 32), blk, 0, stream>>>(proj_w, proj_t, 1024, 4096);
    convert_bf16<<<512, blk, 0, stream>>>(wo, wo_bf, 131072);
    fuse_bias<<<16, blk, 0, stream>>>(bo, proj_w, proj_b, bfused);
    fuse_bias_qkv<<<12, blk, 0, stream>>>(conv_b, wq, bq, wk, bk, wv, bv, b2);

    // WfT[dm][he] = sum_w proj_t[dm][w] * wo_flat[he][w]
    gemm256<1, 0, false><<<dim3(4, 16), blk5, 0, stream>>>(
        proj_t, 1024, wo_bf, 1024, 0, WfT, 1024, nullptr, 16);
    // weight prep: W2T[t][o][i] = sum_d wqkvT[o][d] * conv_w[t][i][(o>>10)*1024+d]
    for (int t = 0; t < 3; ++t)
        gemm256<1, 1, false><<<dim3(16, 12), blk5, 0, stream>>>(
            wq_t, 1024, cw_bf + (size_t)t * 4096 * 3072, 3072, 0,
            W2T + (size_t)t * 3072 * 4096, 4096, nullptr, 16);
    // fused conv+projection as 3-tap GEMM -> qkvh [16384][3072]
    gemm256<3, 0, false><<<dim3(12, 64), blk5, 0, stream>>>(
        in_pad, 4096, W2T, 4096, (long long)3072 * 4096, qkvh, 3072, b2, 192);

    attn_kernel<<<dim3(16, 128), blk, 0, stream>>>(qkvh, o_buf);

    // out = o @ Wf + bfused   (f32 out)
    gemm256<1, 0, true><<<dim3(16, 64), blk5, 0, stream>>>(
        o_buf, 1024, WfT, 1024, 0, d_out, 4096, bfused, 16);
}

// Round 11
// 1665.170 us; speedup vs baseline: 1.1402x; 1.0044x over previous
//
#include <hip/hip_runtime.h>
#include <hip/hip_bf16.h>
#include <stdint.h>

typedef __attribute__((ext_vector_type(8))) short short8;
typedef __attribute__((ext_vector_type(4))) float f32x4;

#define AS1 __attribute__((address_space(1)))
#define AS3 __attribute__((address_space(3)))

__device__ __forceinline__ short f2bf(float x) {
    __hip_bfloat16 h = __float2bfloat16(x);
    union { __hip_bfloat16 h; short s; } u; u.h = h; return u.s;
}

__device__ __forceinline__ void gload_lds16(const short* g, short* l) {
    __builtin_amdgcn_global_load_lds((const AS1 void*)g, (AS3 void*)l, 16, 0, 0);
}

// r11 KEY CHANGE: sync primitives without "memory" clobber. The old
// asm volatile("s_barrier" ::: "memory") forced the compiler to emit a
// hidden s_waitcnt vmcnt(0) lgkmcnt(0) BEFORE the asm (asm could read LDS
// that in-flight global_load_lds writes) -- every "counted" vmcnt in r1-r10
// had a drain-to-0 in front of it, defeating T4. Builtin s_barrier emits no
// drain (the documented reason HK uses it); counted vmcnt via clobber-free
// asm; sched_barrier(0) after each GUARDING sync pins plain ds_reads below
// their residency confirmation (rule #18 analog).
#define SBAR()   __builtin_amdgcn_s_barrier()
#define WAITV(N) asm volatile("s_waitcnt vmcnt(" #N ")")
#define SCHED0() __builtin_amdgcn_sched_barrier(0)

// ---------------------------------------------------------------------------
// r5 schedule (best measured), 256x256 tile, BK=64, 8 waves (2M x 4N),
// 4 phases split on mi, counted vmcnt(4), T2 chunk-XOR swizzle (0 conflicts).
// Ledger: prologue vmcnt(4) confirms t0.kh0; ph1 vmcnt(4) confirms t.kh1;
// ph3 vmcnt(4) confirms (t+1).kh0. Stages: ph0 A-kh0(t+1), ph1 B-kh0(t+1),
// ph2 A-kh1(t+1), ph3 B-kh1(t+1), all into buf nb. Overwrite hazard closed
// by phase barriers (reads complete before their MFMA, which precedes the
// barrier the next stage follows).
// MODE: 0 = plain; 1 = QKVB (weight-prep: B col base += m0 & ~1023).
// TAPS==3: conv path; A rows remap through padded [2][8194][4096].
// ---------------------------------------------------------------------------
template<int TAPS, int MODE, bool F32OUT>
__global__ __launch_bounds__(512, 2) void gemm256(
    const short* __restrict__ A, int lda,
    const short* __restrict__ BT, int ldb, long long tapB,
    void* __restrict__ Cout, int ldc,
    const float* __restrict__ bias, int Ktiles)
{
    __shared__ __align__(16) short As[2 * 2 * 256 * 32];
    __shared__ __align__(16) short Bs[2 * 2 * 256 * 32];
    const int tid = threadIdx.x, lane = tid & 63, wid = tid >> 6;
    const int wm = wid >> 2, wn = wid & 3;
    const int m0 = blockIdx.y * 256, n0 = blockIdx.x * 256;
    const size_t arow0 = (TAPS == 3) ? ((size_t)(m0 >> 13) * 8194 + (size_t)(m0 & 8191))
                                     : (size_t)m0;
    const size_t ldaS = (size_t)lda, ldbS = (size_t)ldb, tapBS = (size_t)tapB;
    const short* Abase0 = A + arow0 * ldaS;
    const short* Bbase0 = BT + (size_t)n0 * ldbS + ((MODE == 1) ? (m0 & ~1023) : 0);
    const int c15 = lane & 15, g4 = (lane >> 4) * 4;
    const int swz = ((lane >> 4) ^ ((c15 >> 1) & 3)) * 8;
    const int srow = tid >> 2;
    const int schunk = (((tid & 3) ^ ((tid >> 3) & 3)) * 8);

#define STG_A(u, kh, buf) do { \
    const int tp_ = (TAPS == 3) ? ((u) >> 6) : 0; \
    const int kc_ = (TAPS == 3) ? (((u) & 63) << 6) : ((u) << 6); \
    const short* g_ = Abase0 + (size_t)tp_ * ldaS + kc_ + (kh) * 32 \
                      + (size_t)srow * ldaS + schunk; \
    short* l_ = As + (buf) * 16384 + (kh) * 8192 + wid * 512; \
    gload_lds16(g_, l_); \
    gload_lds16(g_ + 128 * ldaS, l_ + 4096); \
} while (0)

#define STG_B(u, kh, buf) do { \
    const int tp_ = (TAPS == 3) ? ((u) >> 6) : 0; \
    const int kc_ = (TAPS == 3) ? (((u) & 63) << 6) : ((u) << 6); \
    const short* g_ = Bbase0 + (size_t)tp_ * tapBS + kc_ + (kh) * 32 \
                      + (size_t)srow * ldbS + schunk; \
    short* l_ = Bs + (buf) * 16384 + (kh) * 8192 + wid * 512; \
    gload_lds16(g_, l_); \
    gload_lds16(g_ + 128 * ldbS, l_ + 4096); \
} while (0)

#define LDA_(buf, kk, mi) (*(const short8*)(As + (buf) * 16384 + (kk) * 8192 \
                           + (wm * 128 + (mi) * 16 + c15) * 32 + swz))
#define LDB_(buf, kk, nj) (*(const short8*)(Bs + (buf) * 16384 + (kk) * 8192 \
                           + (wn * 64 + (nj) * 16 + c15) * 32 + swz))

// 16 MFMA: af[0..3] x bf4[0..3] -> acc[MB..MB+3][0..3]
#define MFMA4x4(MB) do { \
    __builtin_amdgcn_s_setprio(1); \
    _Pragma("unroll") \
    for (int mi_ = 0; mi_ < 4; ++mi_) \
        _Pragma("unroll") \
        for (int nj_ = 0; nj_ < 4; ++nj_) \
            acc[(MB) + mi_][nj_] = __builtin_amdgcn_mfma_f32_16x16x32_bf16( \
                af[mi_], bf4[nj_], acc[(MB) + mi_][nj_], 0, 0, 0); \
    __builtin_amdgcn_s_setprio(0); \
} while (0)

    f32x4 acc[8][4];
    #pragma unroll
    for (int i = 0; i < 8; ++i)
        #pragma unroll
        for (int j = 0; j < 4; ++j)
            acc[i][j] = (f32x4){0.f, 0.f, 0.f, 0.f};

    // prologue: tile 0, issue order = Akh0, Bkh0, Akh1, Bkh1 (8 loads)
    STG_A(0, 0, 0); STG_B(0, 0, 0); STG_A(0, 1, 0); STG_B(0, 1, 0);
    WAITV(4); SBAR(); SCHED0();   // kh0 of tile 0 resident; kh1 in flight

    for (int t = 0; t < Ktiles; ++t) {
        const int c = t & 1, nb = c ^ 1;
        const bool st = (t + 1 < Ktiles);
        const int u = t + 1;
        short8 af[4], bf4[4];

        // ---- ph0: kk=0, mi 0-3 (+ all 4 b) ----
        #pragma unroll
        for (int mi = 0; mi < 4; ++mi) af[mi] = LDA_(c, 0, mi);
        #pragma unroll
        for (int nj = 0; nj < 4; ++nj) bf4[nj] = LDB_(c, 0, nj);
        if (st) STG_A(u, 0, nb);
        SBAR();
        MFMA4x4(0);
        SBAR();

        // ---- ph1: kk=0, mi 4-7 (reuse bf4); confirm kh1(t) ----
        #pragma unroll
        for (int mi = 0; mi < 4; ++mi) af[mi] = LDA_(c, 0, 4 + mi);
        if (st) STG_B(u, 0, nb);
        if (st) { WAITV(4); } else { WAITV(0); }
        SBAR(); SCHED0();
        MFMA4x4(4);
        SBAR();

        // ---- ph2: kk=1, mi 0-3 (+ all 4 b) ----
        #pragma unroll
        for (int mi = 0; mi < 4; ++mi) af[mi] = LDA_(c, 1, mi);
        #pragma unroll
        for (int nj = 0; nj < 4; ++nj) bf4[nj] = LDB_(c, 1, nj);
        if (st) STG_A(u, 1, nb);
        SBAR();
        MFMA4x4(0);
        SBAR();

        // ---- ph3: kk=1, mi 4-7 (reuse bf4); confirm kh0(t+1) ----
        #pragma unroll
        for (int mi = 0; mi < 4; ++mi) af[mi] = LDA_(c, 1, 4 + mi);
        if (st) STG_B(u, 1, nb);
        if (st) { WAITV(4); } else { WAITV(0); }
        SBAR(); SCHED0();
        MFMA4x4(4);
        SBAR();
    }

    float bv[4];
    #pragma unroll
    for (int nj = 0; nj < 4; ++nj)
        bv[nj] = bias ? bias[n0 + wn * 64 + nj * 16 + c15] : 0.f;
    #pragma unroll
    for (int mi = 0; mi < 8; ++mi) {
        #pragma unroll
        for (int r = 0; r < 4; ++r) {
            const size_t row = (size_t)m0 + wm * 128 + mi * 16 + g4 + r;
            #pragma unroll
            for (int nj = 0; nj < 4; ++nj) {
                const int col = n0 + wn * 64 + nj * 16 + c15;
                const float v = acc[mi][nj][r] + bv[nj];
                if (F32OUT) ((float*)Cout)[row * (size_t)ldc + col] = v;
                else        ((short*)Cout)[row * (size_t)ldc + col] = f2bf(v);
            }
        }
    }
#undef STG_A
#undef STG_B
#undef LDA_
#undef LDB_
#undef MFMA4x4
}

// ---------------------------------------------------------------------------
// Per (head, block) causal attention. qkvh: [16384][3072] bf16, q at cols
// 0-1023, k at +1024, v at +2048 (col within each = h*64+e). obuf [16384][1024].
// ---------------------------------------------------------------------------
__global__ __launch_bounds__(256) void attn_kernel(
    const short* __restrict__ qkvh, short* __restrict__ obuf)
{
    __shared__ __align__(16) char smem[54272];
    short* qs = (short*)smem;                 // [128][72]
    short* ks = (short*)smem + 9216;          // [128][72]
    short* vt = (short*)(smem + 36864);       // [64][136]  (v transposed)
    short* ps = (short*)smem;                 // [128][136] (reuses qs+ks region)
    short* os = (short*)smem;                 // [128][72]  (reused post-PV)

    const int tid = threadIdx.x, lane = tid & 63, wid = tid >> 6;
    const int h = blockIdx.x, b = blockIdx.y;
    const size_t base = (size_t)b * 128 * 3072 + (size_t)h * 64;

    for (int i = tid; i < 1024; i += 256) {
        const int row = i >> 3, c8 = i & 7;
        const size_t g = base + (size_t)row * 3072 + c8 * 8;
        *(short8*)(qs + row * 72 + c8 * 8) = *(const short8*)(qkvh + g);
        *(short8*)(ks + row * 72 + c8 * 8) = *(const short8*)(qkvh + g + 1024);
        short8 vv = *(const short8*)(qkvh + g + 2048);
        #pragma unroll
        for (int j = 0; j < 8; ++j) vt[(c8 * 8 + j) * 136 + row] = vv[j];
    }
    __syncthreads();

    const int c15 = lane & 15, g8 = (lane >> 4) * 8, g4 = (lane >> 4) * 4;
    const int r0 = wid * 32;

    f32x4 sacc[2][8];
    #pragma unroll
    for (int mi = 0; mi < 2; ++mi)
        #pragma unroll
        for (int nj = 0; nj < 8; ++nj)
            sacc[mi][nj] = (f32x4){0.f, 0.f, 0.f, 0.f};
    #pragma unroll
    for (int kk = 0; kk < 2; ++kk) {
        short8 aq[2];
        #pragma unroll
        for (int mi = 0; mi < 2; ++mi)
            aq[mi] = *(const short8*)(qs + (r0 + mi * 16 + c15) * 72 + kk * 32 + g8);
        #pragma unroll
        for (int nj = 0; nj < 8; ++nj) {
            short8 bk8 = *(const short8*)(ks + (nj * 16 + c15) * 72 + kk * 32 + g8);
            #pragma unroll
            for (int mi = 0; mi < 2; ++mi)
                sacc[mi][nj] = __builtin_amdgcn_mfma_f32_16x16x32_bf16(
                    aq[mi], bk8, sacc[mi][nj], 0, 0, 0);
        }
    }
    __syncthreads();

    #pragma unroll
    for (int mi = 0; mi < 2; ++mi) {
        #pragma unroll
        for (int r = 0; r < 4; ++r) {
            const int qrow = r0 + mi * 16 + g4 + r;
            float m = -3.0e38f, pv[8];
            #pragma unroll
            for (int nj = 0; nj < 8; ++nj) {
                float s = sacc[mi][nj][r] * 0.125f;
                if (nj * 16 + c15 > qrow) s = -1.0e9f;
                pv[nj] = s; m = fmaxf(m, s);
            }
            #pragma unroll
            for (int off = 8; off >= 1; off >>= 1) m = fmaxf(m, __shfl_xor(m, off));
            float sum = 0.f;
            #pragma unroll
            for (int nj = 0; nj < 8; ++nj) { float p = __expf(pv[nj] - m); pv[nj] = p; sum += p; }
            #pragma unroll
            for (int off = 8; off >= 1; off >>= 1) sum += __shfl_xor(sum, off);
            const float inv = 1.0f / sum;
            #pragma unroll
            for (int nj = 0; nj < 8; ++nj)
                ps[qrow * 136 + nj * 16 + c15] = f2bf(pv[nj] * inv);
        }
    }
    __syncthreads();

    f32x4 oacc[2][4];
    #pragma unroll
    for (int mi = 0; mi < 2; ++mi)
        #pragma unroll
        for (int nj = 0; nj < 4; ++nj)
            oacc[mi][nj] = (f32x4){0.f, 0.f, 0.f, 0.f};
    #pragma unroll
    for (int kt = 0; kt < 4; ++kt) {
        short8 ap[2];
        #pragma unroll
        for (int mi = 0; mi < 2; ++mi)
            ap[mi] = *(const short8*)(ps + (r0 + mi * 16 + c15) * 136 + kt * 32 + g8);
        #pragma unroll
        for (int nj = 0; nj < 4; ++nj) {
            short8 bv8 = *(const short8*)(vt + (nj * 16 + c15) * 136 + kt * 32 + g8);
            #pragma unroll
            for (int mi = 0; mi < 2; ++mi)
                oacc[mi][nj] = __builtin_amdgcn_mfma_f32_16x16x32_bf16(
                    ap[mi], bv8, oacc[mi][nj], 0, 0, 0);
        }
    }
    __syncthreads();

    #pragma unroll
    for (int mi = 0; mi < 2; ++mi)
        #pragma unroll
        for (int r = 0; r < 4; ++r)
            #pragma unroll
            for (int nj = 0; nj < 4; ++nj)
                os[(r0 + mi * 16 + g4 + r) * 72 + nj * 16 + c15] = f2bf(oacc[mi][nj][r]);
    __syncthreads();

    for (int i = tid; i < 1024; i += 256) {
        const int row = i >> 3, c8 = i & 7;
        *(short8*)(obuf + (size_t)b * 128 * 1024 + (size_t)h * 64
                   + (size_t)row * 1024 + c8 * 8) =
            *(const short8*)(os + row * 72 + c8 * 8);
    }
}

// ---------------------------------------------------------------------------
__global__ void pad_convert_inputs(const float* __restrict__ in, short* __restrict__ out)
{
    const int row = blockIdx.x;                 // [0, 16388)
    const int n = row / 8194, l = row % 8194;
    short* orow = out + (size_t)row * 4096;
    if (l == 0 || l == 8193) {
        for (int i = threadIdx.x; i < 512; i += 256) {
            uint4 z; z.x = z.y = z.z = z.w = 0u;
            *(uint4*)(orow + i * 8) = z;
        }
    } else {
        const float* irow = in + ((size_t)n * 8192 + (l - 1)) * 4096;
        for (int i = threadIdx.x; i < 512; i += 256) {
            float4 a = *(const float4*)(irow + i * 8);
            float4 b = *(const float4*)(irow + i * 8 + 4);
            short8 v;
            v[0] = f2bf(a.x); v[1] = f2bf(a.y); v[2] = f2bf(a.z); v[3] = f2bf(a.w);
            v[4] = f2bf(b.x); v[5] = f2bf(b.y); v[6] = f2bf(b.z); v[7] = f2bf(b.w);
            *(short8*)(orow + i * 8) = v;
        }
    }
}

__global__ void transpose_convert(const float* __restrict__ in, short* __restrict__ out,
                                  int R, int C)
{
    __shared__ float tile[32][33];
    const int tx = threadIdx.x & 31, ty = threadIdx.x >> 5;   // 32 x 8
    const int bx = blockIdx.x * 32, by = blockIdx.y * 32;
    #pragma unroll
    for (int i = 0; i < 32; i += 8)
        tile[ty + i][tx] = in[(size_t)(by + ty + i) * C + bx + tx];
    __syncthreads();
    #pragma unroll
    for (int i = 0; i < 32; i += 8)
        out[(size_t)(bx + ty + i) * R + by + tx] = f2bf(tile[tx][ty + i]);
}

__global__ void convert_bf16(const float* __restrict__ in, short* __restrict__ out, int n8)
{
    const int idx = blockIdx.x * 256 + threadIdx.x;
    if (idx < n8) {
        float4 a = *(const float4*)(in + (size_t)idx * 8);
        float4 b = *(const float4*)(in + (size_t)idx * 8 + 4);
        short8 v;
        v[0] = f2bf(a.x); v[1] = f2bf(a.y); v[2] = f2bf(a.z); v[3] = f2bf(a.w);
        v[4] = f2bf(b.x); v[5] = f2bf(b.y); v[6] = f2bf(b.z); v[7] = f2bf(b.w);
        *(short8*)(out + (size_t)idx * 8) = v;
    }
}

__global__ void fuse_bias(const float* __restrict__ bo, const float* __restrict__ projw,
                          const float* __restrict__ projb, float* __restrict__ outb)
{
    const int j = blockIdx.x * 256 + threadIdx.x;   // 4096
    float s = projb[j];
    for (int w = 0; w < 1024; ++w) s = fmaf(bo[w], projw[(size_t)w * 4096 + j], s);
    outb[j] = s;
}

// b2[o] = b_part[o&1023] + sum_d conv_b[(o>>10)*1024+d] * wpart[d][o&1023]
__global__ void fuse_bias_qkv(const float* __restrict__ conv_b,
                              const float* __restrict__ wq, const float* __restrict__ bq,
                              const float* __restrict__ wk, const float* __restrict__ bk,
                              const float* __restrict__ wv, const float* __restrict__ bv,
                              float* __restrict__ outb)
{
    const int o = blockIdx.x * 256 + threadIdx.x;   // 3072
    const int p = o >> 10, e = o & 1023;
    const float* w = (p == 0) ? wq : (p == 1) ? wk : wv;
    const float* bb = (p == 0) ? bq : (p == 1) ? bk : bv;
    const float* cb = conv_b + p * 1024;
    float s = bb[e];
    for (int d = 0; d < 1024; ++d) s = fmaf(cb[d], w[(size_t)d * 1024 + e], s);
    outb[o] = s;
}

// ---------------------------------------------------------------------------
extern "C" void kernel_launch(void* const* d_in, const int* in_sizes, int n_in,
                              void* d_out, int out_size, void* d_ws, size_t ws_size,
                              hipStream_t stream)
{
    const float* inputs = (const float*)d_in[0];
    const float* conv_w = (const float*)d_in[1];
    const float* conv_b = (const float*)d_in[2];
    const float* wq     = (const float*)d_in[3];
    const float* bq     = (const float*)d_in[4];
    const float* wk     = (const float*)d_in[5];
    const float* bk     = (const float*)d_in[6];
    const float* wv     = (const float*)d_in[7];
    const float* bv     = (const float*)d_in[8];
    const float* wo     = (const float*)d_in[9];
    const float* bo     = (const float*)d_in[10];
    const float* proj_w = (const float*)d_in[11];
    const float* proj_b = (const float*)d_in[12];

    char* ws = (char*)d_ws;
    short* in_pad = (short*)(ws + 0);             // [2][8194][4096]      134,283,264 B
    short* cw_bf  = (short*)(ws + 134283264);     // [3][4096][3072] bf16 (dead after prep)
    short* qkvh   = (short*)(ws + 134283264);     // [16384][3072] over cw_bf
    short* W2T    = (short*)(ws + 234946560);     // [3][3072][4096] bf16
    short* wq_t   = (short*)(ws + 310444032);     // [3][1024][1024] BT contiguous
    short* wo_bf  = (short*)(ws + 316735488);     // [1024][1024]
    short* proj_t = (short*)(ws + 318832640);     // [4096][1024]
    short* WfT    = (short*)(ws + 327221248);     // [4096][1024]
    float* bfused = (float*)(ws + 335609856);     // [4096]
    float* b2     = (float*)(ws + 335626240);     // [3072]
    short* o_buf  = (short*)(ws + 0);             // [16384][1024] over in_pad

    dim3 blk(256), blk5(512);

    pad_convert_inputs<<<16388, blk, 0, stream>>>(inputs, in_pad);
    convert_bf16<<<18432, blk, 0, stream>>>(conv_w, cw_bf, 4718592);   // straight convert
    transpose_convert<<<dim3(32, 32), blk, 0, stream>>>(wq, wq_t, 1024, 1024);
    transpose_convert<<<dim3(32, 32), blk, 0, stream>>>(wk, wq_t + 1048576, 1024, 1024);
    transpose_convert<<<dim3(32, 32), blk, 0, stream>>>(wv, wq_t + 2097152, 1024, 1024);
    transpose_convert<<<dim3(128, 32), blk, 0, stream>>>(proj_w, proj_t, 1024, 4096);
    convert_bf16<<<512, blk, 0, stream>>>(wo, wo_bf, 131072);
    fuse_bias<<<16, blk, 0, stream>>>(bo, proj_w, proj_b, bfused);
    fuse_bias_qkv<<<12, blk, 0, stream>>>(conv_b, wq, bq, wk, bk, wv, bv, b2);

    // WfT[dm][he] = sum_w proj_t[dm][w] * wo_flat[he][w]
    gemm256<1, 0, false><<<dim3(4, 16), blk5, 0, stream>>>(
        proj_t, 1024, wo_bf, 1024, 0, WfT, 1024, nullptr, 16);
    // weight prep: W2T[t][o][i] = sum_d wqkvT[o][d] * conv_w[t][i][(o>>10)*1024+d]
    for (int t = 0; t < 3; ++t)
        gemm256<1, 1, false><<<dim3(16, 12), blk5, 0, stream>>>(
            wq_t, 1024, cw_bf + (size_t)t * 4096 * 3072, 3072, 0,
            W2T + (size_t)t * 3072 * 4096, 4096, nullptr, 16);
    // fused conv+projection as 3-tap GEMM -> qkvh [16384][3072]
    gemm256<3, 0, false><<<dim3(12, 64), blk5, 0, stream>>>(
        in_pad, 4096, W2T, 4096, (long long)3072 * 4096, qkvh, 3072, b2, 192);

    attn_kernel<<<dim3(16, 128), blk, 0, stream>>>(qkvh, o_buf);

    // out = o @ Wf + bfused   (f32 out)
    gemm256<1, 0, true><<<dim3(16, 64), blk5, 0, stream>>>(
        o_buf, 1024, WfT, 1024, 0, d_out, 4096, bfused, 16);
}